// Round 8
// baseline (31.497 us; speedup 1.0000x reference)
//
#include <hip/hip_runtime.h>
#include <hip/hip_bf16.h>
#include <float.h>

// Problem constants: B=16, M=4096.
#define NB 16
#define MPTS 4096
#define NPRED (NB * MPTS)        // 65536
#define NT 128                   // gt tiles of 32 per batch
#define CHUNK 32                 // tiles per LDS chunk (32 KB)
#define NCHUNK (NT / CHUNK)      // 4
#define BLK 256                  // 4 waves
#define PREDS_PER_BLK 128        // 1 MFMA B-frag (32 preds) per wave
#define PG (MPTS / PREDS_PER_BLK)// 32 pred groups per batch
#define MAIN_BLOCKS (NB * PG)    // 512

typedef _Float16 half8 __attribute__((ext_vector_type(8)));
typedef float f32x16 __attribute__((ext_vector_type(16)));

__device__ inline void split16(float x, _Float16& hi, _Float16& lo) {
    hi = (_Float16)x;
    lo = (_Float16)(x - (float)hi);
}

// Kernel 1: transform + hi/lo-split + MFMA-layout-pack all gt points, once.
// A[b][t][lane] half8, lane = (khalf)*32 + row:
//   kh0: [hux,huy,huz,hux,huy,huz,lux,luy]   (u = -2g)
//   kh1: [luz,gnh,gnl,0,0,0,0,0]             (gn = ||g||^2)
__global__ __launch_bounds__(256) void adds_pack(
    const float* __restrict__ gt_R, const float* __restrict__ gt_t,
    const float* __restrict__ mp,   half8* __restrict__ A)
{
    const int b = blockIdx.x >> 4;                      // 16 blocks per batch
    const int n = ((blockIdx.x & 15) << 8) + threadIdx.x;

    float gR[9];
#pragma unroll
    for (int i = 0; i < 9; ++i) gR[i] = gt_R[b * 9 + i];
    const float mx = mp[n * 3 + 0];
    const float my = mp[n * 3 + 1];
    const float mz = mp[n * 3 + 2];
    const float gx = fmaf(gR[0], mx, fmaf(gR[1], my, fmaf(gR[2], mz, gt_t[b * 3 + 0])));
    const float gy = fmaf(gR[3], mx, fmaf(gR[4], my, fmaf(gR[5], mz, gt_t[b * 3 + 1])));
    const float gz = fmaf(gR[6], mx, fmaf(gR[7], my, fmaf(gR[8], mz, gt_t[b * 3 + 2])));
    const float gn = fmaf(gx, gx, fmaf(gy, gy, gz * gz));
    const float ux = -2.0f * gx, uy = -2.0f * gy, uz = -2.0f * gz;

    _Float16 hux, lux, huy, luy, huz, luz, gnh, gnl;
    split16(ux, hux, lux);
    split16(uy, huy, luy);
    split16(uz, huz, luz);
    split16(gn, gnh, gnl);

    half8 k0, k1;
    k0[0] = hux; k0[1] = huy; k0[2] = huz;
    k0[3] = hux; k0[4] = huy; k0[5] = huz;
    k0[6] = lux; k0[7] = luy;
    k1[0] = luz; k1[1] = gnh; k1[2] = gnl;
    k1[3] = (_Float16)0.0f; k1[4] = (_Float16)0.0f; k1[5] = (_Float16)0.0f;
    k1[6] = (_Float16)0.0f; k1[7] = (_Float16)0.0f;

    const int t = n >> 5, r = n & 31;
    A[((b * NT + t) << 6) + r]      = k0;
    A[((b * NT + t) << 6) + 32 + r] = k1;
}

// Kernel 2: one block = (batch b, 128-pred group). Loops ALL gt tiles, so the
// per-pred min completes in-block (no pmin buffer). A streamed global->LDS via
// global_load_lds, double-buffered 32KB chunks. Per tile: 1 ds_read_b128 +
// 1 mfma_32x32x16_f16 + 8 v_min3. Epilogue: sqrt + block sum -> partial[bid].
__global__ __launch_bounds__(BLK, 2) void adds_main(
    const float* __restrict__ pred_R, const float* __restrict__ pred_t,
    const float* __restrict__ mp,     const half8* __restrict__ A,
    float* __restrict__ partial)
{
    __shared__ half8 lds[2][CHUNK * 64];     // 64 KB
    __shared__ float wsum[4];

    const int bid = blockIdx.x;
    const int b   = bid >> 5;
    const int pg  = bid & 31;
    const int tid = threadIdx.x;
    const int ln  = tid & 63;
    const int wv  = tid >> 6;
    const int kh  = ln >> 5;

    const half8* Ab = A + (size_t)b * NT * 64;

    // issue one 32KB chunk: 8 x 16B per thread, wave-contiguous (linear LDS)
    auto ISSUE = [&](int c) {
        const half8* src = Ab + c * CHUNK * 64;
        half8* dst = &lds[c & 1][0];
#pragma unroll
        for (int j = 0; j < 8; ++j) {
            const int e = wv * 512 + j * 64 + ln;
            __builtin_amdgcn_global_load_lds(
                (const __attribute__((address_space(1))) void*)(src + e),
                (__attribute__((address_space(3))) void*)(dst + e), 16, 0, 0);
        }
    };

    ISSUE(0);

    // ---- B fragment (this wave's 32 preds) ----
    float pR[9];
#pragma unroll
    for (int i = 0; i < 9; ++i) pR[i] = pred_R[b * 9 + i];
    const int predl = pg * PREDS_PER_BLK + wv * 32 + (ln & 31);
    const float mx = mp[predl * 3 + 0];
    const float my = mp[predl * 3 + 1];
    const float mz = mp[predl * 3 + 2];
    const float px = fmaf(pR[0], mx, fmaf(pR[1], my, fmaf(pR[2], mz, pred_t[b * 3 + 0])));
    const float py = fmaf(pR[3], mx, fmaf(pR[4], my, fmaf(pR[5], mz, pred_t[b * 3 + 1])));
    const float pz = fmaf(pR[6], mx, fmaf(pR[7], my, fmaf(pR[8], mz, pred_t[b * 3 + 2])));
    const float pn = fmaf(px, px, fmaf(py, py, pz * pz));

    _Float16 hpx, lpx, hpy, lpy, hpz, lpz;
    split16(px, hpx, lpx);
    split16(py, hpy, lpy);
    split16(pz, hpz, lpz);
    half8 bf;
    if (kh == 0) {
        bf[0] = hpx; bf[1] = hpy; bf[2] = hpz;
        bf[3] = lpx; bf[4] = lpy; bf[5] = lpz;
        bf[6] = hpx; bf[7] = hpy;
    } else {
        bf[0] = hpz; bf[1] = (_Float16)1.0f; bf[2] = (_Float16)1.0f;
        bf[3] = (_Float16)0.0f; bf[4] = (_Float16)0.0f; bf[5] = (_Float16)0.0f;
        bf[6] = (_Float16)0.0f; bf[7] = (_Float16)0.0f;
    }

    f32x16 zc;
#pragma unroll
    for (int i = 0; i < 16; ++i) zc[i] = 0.0f;

    float best[8];
#pragma unroll
    for (int j = 0; j < 8; ++j) best[j] = FLT_MAX;

    __syncthreads();   // drains vmcnt(0): chunk 0 resident

    for (int c = 0; c < NCHUNK; ++c) {
        if (c + 1 < NCHUNK) ISSUE(c + 1);        // prefetch into other buffer
        const half8* buf = &lds[c & 1][0];
#pragma unroll 4
        for (int t = 0; t < CHUNK; ++t) {
            const half8 a = buf[t * 64 + ln];
            const f32x16 d = __builtin_amdgcn_mfma_f32_32x32x16_f16(a, bf, zc, 0, 0, 0);
#pragma unroll
            for (int j = 0; j < 8; ++j)
                best[j] = fminf(best[j], fminf(d[2 * j], d[2 * j + 1]));   // v_min3
        }
        __syncthreads();   // drains vmcnt+lgkmcnt, joins waves for buffer swap
    }

    // ---- epilogue: fold, merge k-halves, sqrt, block sum ----
    float r = fminf(fminf(fminf(best[0], best[1]), fminf(best[2], best[3])),
                    fminf(fminf(best[4], best[5]), fminf(best[6], best[7])));
    r = fminf(r, __shfl_xor(r, 32, 64));
    const float dist = sqrtf(fmaxf(pn + r, 0.0f));

    float s = dist;            // lanes l and l+32 hold the same pred -> x2
#pragma unroll
    for (int off = 32; off > 0; off >>= 1) s += __shfl_down(s, off, 64);
    if (ln == 0) wsum[wv] = s * 0.5f;
    __syncthreads();
    if (tid == 0) partial[bid] = (wsum[0] + wsum[1]) + (wsum[2] + wsum[3]);
}

// Kernel 3: 512 partials -> mean (single small block).
__global__ __launch_bounds__(256) void adds_finish(
    const float* __restrict__ partial, float* __restrict__ out)
{
    __shared__ float wsum[4];
    const int tid = threadIdx.x;
    float s = partial[tid] + partial[256 + tid];
#pragma unroll
    for (int off = 32; off > 0; off >>= 1) s += __shfl_down(s, off, 64);
    if ((tid & 63) == 0) wsum[tid >> 6] = s;
    __syncthreads();
    if (tid == 0)
        out[0] = ((wsum[0] + wsum[1]) + (wsum[2] + wsum[3])) * (1.0f / (float)NPRED);
}

extern "C" void kernel_launch(void* const* d_in, const int* in_sizes, int n_in,
                              void* d_out, int out_size, void* d_ws, size_t ws_size,
                              hipStream_t stream) {
    const float* pred_R = (const float*)d_in[0];
    const float* pred_t = (const float*)d_in[1];
    const float* gt_R   = (const float*)d_in[2];
    const float* gt_t   = (const float*)d_in[3];
    const float* mp     = (const float*)d_in[4];
    float* out = (float*)d_out;

    char* ws = (char*)d_ws;
    half8* Apk     = (half8*)ws;                                   // 16*128*64*16 = 2 MB
    float* partial = (float*)(ws + (size_t)NB * NT * 64 * sizeof(half8)); // 512 floats

    adds_pack<<<dim3(NB * 16), dim3(256), 0, stream>>>(gt_R, gt_t, mp, Apk);
    adds_main<<<dim3(MAIN_BLOCKS), dim3(BLK), 0, stream>>>(
        pred_R, pred_t, mp, Apk, partial);
    adds_finish<<<dim3(1), dim3(256), 0, stream>>>(partial, out);
}